// Round 7
// baseline (17618.895 us; speedup 1.0000x reference)
//
#include <hip/hip_runtime.h>
#include <cstdint>
#include <cstddef>

typedef __attribute__((ext_vector_type(8))) short bf16x8;
typedef __attribute__((ext_vector_type(4))) float f32x4;
#define DEVI __device__ __forceinline__

constexpr int B = 256, S = 128, V = 128, C = 16, H = 1024, Z = 256, NSTEP = 128;
constexpr int VC = V * C, G3 = 3 * H;
constexpr size_t BVC = (size_t)B * VC;
constexpr int RS = 1032;          // padded LDS panel row stride (ush)

DEVI unsigned short f2bf(float f){unsigned u=__float_as_uint(f);u+=0x7fffu+((u>>16)&1u);return (unsigned short)(u>>16);}
DEVI float sigm(float x){return 1.f/(1.f+expf(-x));}
DEVI f32x4 MFMA(bf16x8 a,bf16x8 b,f32x4 c){return __builtin_amdgcn_mfma_f32_16x16x32_bf16(a,b,c,0,0,0);}

DEVI unsigned long long ldc8(const void* p){return __hip_atomic_load((const unsigned long long*)p,__ATOMIC_RELAXED,__HIP_MEMORY_SCOPE_AGENT);}
DEVI void stc8(void* p, unsigned long long v){__hip_atomic_store((unsigned long long*)p,v,__ATOMIC_RELAXED,__HIP_MEMORY_SCOPE_AGENT);}
DEVI unsigned ldc4(const void* p){return __hip_atomic_load((const unsigned*)p,__ATOMIC_RELAXED,__HIP_MEMORY_SCOPE_AGENT);}
DEVI void stc4(void* p, unsigned v){__hip_atomic_store((unsigned*)p,v,__ATOMIC_RELAXED,__HIP_MEMORY_SCOPE_AGENT);}
DEVI unsigned long long pack4(float a,float b,float c,float d){
  return (unsigned long long)f2bf(a)|((unsigned long long)f2bf(b)<<16)|((unsigned long long)f2bf(c)<<32)|((unsigned long long)f2bf(d)<<48);
}
DEVI unsigned long long packf2(float a,float b){
  return (unsigned long long)__float_as_uint(a)|((unsigned long long)__float_as_uint(b)<<32);
}
DEVI void cmb(){asm volatile("" ::: "memory");}
DEVI void drain(){asm volatile("s_waitcnt vmcnt(0) lgkmcnt(0)":::"memory");}

// lanes<n poll flag[base+lane]; seq in high 8 bits; returns flag word
DEVI unsigned waitseq(const unsigned* f,int base,int n,unsigned tgt){
  int lane=threadIdx.x&63; unsigned v=tgt<<24;
  if (lane<n){
    const unsigned* a=&f[(size_t)(base+lane)<<4];
    v=ldc4(a);
    while ((v>>24)<tgt){__builtin_amdgcn_s_sleep(1); v=ldc4(a);}
  }
  cmb();
  return v;
}

// ---------------- prep kernels ----------------
__global__ void k_cvt(const float* __restrict__ src, unsigned short* __restrict__ dst, int n){
  for (int i=blockIdx.x*256+threadIdx.x;i<n;i+=gridDim.x*256) dst[i]=f2bf(src[i]);
}

__global__ void k_xt(const float* __restrict__ x, unsigned short* __restrict__ xtb){
  __shared__ float tile[32][33];
  int sb=blockIdx.x*32, rb=blockIdx.y*32, tx=threadIdx.x, ty=threadIdx.y;
  for (int i=ty;i<32;i+=8) tile[i][tx]=x[(size_t)(rb+i)*S+sb+tx];
  __syncthreads();
  for (int i=ty;i<32;i+=8) xtb[(size_t)(sb+i)*(B*V)+rb+tx]=f2bf(tile[tx][i]);
}

__global__ void k_wt(const float* __restrict__ w, float* __restrict__ wt){
  __shared__ float tile[32][33];
  int vb=blockIdx.x*32, nb=blockIdx.y*32, tx=threadIdx.x, ty=threadIdx.y;
  for (int i=ty;i<32;i+=8) tile[i][tx]=w[(size_t)(nb+i)*(VC+Z)+vb+tx];
  __syncthreads();
  for (int i=ty;i<32;i+=8) wt[(size_t)(vb+i)*G3+nb+tx]=tile[tx][i];
}

__global__ __launch_bounds__(256) void k_mu_var_z(const float* __restrict__ hf,const float* __restrict__ hb,
    const float* __restrict__ Wmu,const float* __restrict__ bmu,
    const float* __restrict__ Wvar,const float* __restrict__ bvar,
    const float* __restrict__ noise,
    float* __restrict__ omu,float* __restrict__ ovar,float* __restrict__ oz,float* __restrict__ zws){
  __shared__ float e[2*H];
  int b=blockIdx.x, t=threadIdx.x;
  for (int i=0;i<2*H/256;++i){int k=t+i*256; e[k]=(k<H)?hf[b*H+k]:hb[b*H+k-H];}
  __syncthreads();
  const float* wm=Wmu+(size_t)t*2*H; const float* wv2=Wvar+(size_t)t*2*H;
  float am=bmu[t], av=bvar[t];
  for (int k=0;k<2*H;++k){am+=e[k]*wm[k];av+=e[k]*wv2[k];}
  float vv=expf(av), zz=am+vv*noise[b*Z+t];
  omu[b*Z+t]=am; ovar[b*Z+t]=vv; oz[b*Z+t]=zz; zws[b*Z+t]=zz;
}

__global__ void k_zpart(const float* __restrict__ z,const float* __restrict__ c1Wih,
                        const float* __restrict__ bih,float* __restrict__ zpart){
  int idx=blockIdx.x*256+threadIdx.x;
  int b=idx/G3, n=idx%G3;
  const float* w=c1Wih+(size_t)n*(VC+Z)+VC;
  const float* zr=z+b*Z;
  float a=bih[n];
  for (int k=0;k<Z;++k) a+=zr[k]*w[k];
  zpart[idx]=a;
}

__global__ void k_h1init(const float* __restrict__ z,const float* __restrict__ Winit,
                         const float* __restrict__ binit,
                         float* __restrict__ h1f,unsigned short* __restrict__ h1b,unsigned* __restrict__ F4){
  int idx=blockIdx.x*256+threadIdx.x;
  int b=idx>>10, jj=idx&(H-1);
  const float* w=Winit+(size_t)jj*Z;
  const float* zr=z+b*Z;
  float a=binit[jj];
  for (int k=0;k<Z;++k) a+=zr[k]*w[k];
  float t=tanhf(a);
  h1f[idx]=t; h1b[idx]=f2bf(t);
  if (idx<128) F4[(size_t)idx<<4]=((unsigned)(VC-1)<<12)|(unsigned)(VC-1); // seq 0
}

// ---------------- persistent encoder: 256 blocks x 512 thr ----------------
// bid = dir*128 + mgrp*16 + jt ; mgrp 0..7 (32 rows), jt 0..15 (64 cols)
struct EncP {
  const unsigned short *xtb,*wihf,*whhf,*wihb,*whhb;
  const float *bihf,*bhhf,*bihb,*bhhb;
  unsigned short *hf0,*hf1,*hb0,*hb1;
  float *hf,*hb;
  unsigned* FE;
};

__global__ __launch_bounds__(512,1) void k_enc(EncP P){
  __shared__ unsigned short L[37376];          // panel [32][RS] @0, X [32][136] @33024
  const int XB=33024;
  const int tid=threadIdx.x, wave=tid>>6, lane=tid&63;
  const int l15=lane&15, l4=lane>>4;
  const int bid=blockIdx.x, jt=bid&15, mgrp=(bid>>4)&7, dir=bid>>7;
  const int g16=bid&~15;
  const int jt4=wave>>1, mi=wave&1;
  const int jrow=jt*64+jt4*16+l15;
  const int j0=jt*64+jt4*16+(l4<<2);
  const int m=mgrp*32+mi*16+l15;
  const unsigned short* __restrict__ wih=dir?P.wihb:P.wihf;
  const unsigned short* __restrict__ whh=dir?P.whhb:P.whhf;
  const float* bih=dir?P.bihb:P.bihf;
  const float* bhh=dir?P.bhhb:P.bhhf;
  unsigned short* hbuf[2]={dir?P.hb0:P.hf0, dir?P.hb1:P.hf1};

  f32x4 cR,cZ,bNi,bNh;
  { f32x4 a=*(const f32x4*)&bih[j0],   b2=*(const f32x4*)&bhh[j0];   cR=a+b2; }
  { f32x4 a=*(const f32x4*)&bih[H+j0], b2=*(const f32x4*)&bhh[H+j0]; cZ=a+b2; }
  bNi=*(const f32x4*)&bih[2*H+j0]; bNh=*(const f32x4*)&bhh[2*H+j0];
  float hreg[4]={};

  for (int s=0;s<S;++s){
    const int xs=dir?(S-1-s):s;
    __syncthreads();                       // all waves done reading prev panel/X
    // X load (plain cached)
    { int row=tid>>4, c=tid&15;
      uint4 v=*(const uint4*)&P.xtb[(size_t)xs*(B*V)+(size_t)(mgrp*32+row)*V+(c<<3)];
      *(uint4*)&L[XB + row*136 + (c<<3)]=v; }
    // telescoped panel gather: 16 slices x 32 threads
    { const int p=tid>>5, u=tid&31;
      const unsigned* fa=&P.FE[(size_t)(g16+p)<<4];
      while (ldc4(fa)<(unsigned)s) __builtin_amdgcn_s_sleep(1);
      cmb();
      const unsigned short* src=hbuf[s&1] + (size_t)(mgrp*32+u)*H + p*64;
      unsigned long long q[16];
#pragma unroll
      for (int i=0;i<16;++i) q[i]=ldc8(src+i*4);
      unsigned short* d=&L[u*RS + p*64];
#pragma unroll
      for (int i=0;i<16;++i) *(unsigned long long*)&d[i*4]=q[i];
    }
    __syncthreads();
    f32x4 aR={},aZ={},aNH={},aNX={};
#pragma unroll 4
    for (int kk=0;kk<32;++kk){
      bf16x8 b=*(const bf16x8*)&L[(mi*16+l15)*RS + kk*32 + l4*8];
      bf16x8 a0=*(const bf16x8*)&whh[(size_t)(jrow      )*H + kk*32 + l4*8];
      bf16x8 a1=*(const bf16x8*)&whh[(size_t)(H   +jrow )*H + kk*32 + l4*8];
      bf16x8 a2=*(const bf16x8*)&whh[(size_t)(2*H +jrow )*H + kk*32 + l4*8];
      aR=MFMA(a0,b,aR); aZ=MFMA(a1,b,aZ); aNH=MFMA(a2,b,aNH);
    }
#pragma unroll
    for (int kk=0;kk<4;++kk){
      bf16x8 b=*(const bf16x8*)&L[XB + (mi*16+l15)*136 + kk*32 + l4*8];
      bf16x8 a0=*(const bf16x8*)&wih[(size_t)(jrow      )*V + kk*32 + l4*8];
      bf16x8 a1=*(const bf16x8*)&wih[(size_t)(H   +jrow )*V + kk*32 + l4*8];
      bf16x8 a2=*(const bf16x8*)&wih[(size_t)(2*H +jrow )*V + kk*32 + l4*8];
      aR=MFMA(a0,b,aR); aZ=MFMA(a1,b,aZ); aNX=MFMA(a2,b,aNX);
    }
    float hv[4];
#pragma unroll
    for (int r=0;r<4;++r){
      float rg=sigm(aR[r]+cR[r]);
      float zg=sigm(aZ[r]+cZ[r]);
      float nn=tanhf(aNX[r]+bNi[r]+rg*(aNH[r]+bNh[r]));
      float hnew=(1.f-zg)*nn+zg*hreg[r];
      hreg[r]=hnew; hv[r]=hnew;
    }
    stc8(hbuf[(s+1)&1] + (size_t)m*H + j0, pack4(hv[0],hv[1],hv[2],hv[3]));
    drain(); __syncthreads();
    if (tid==0) stc4(&P.FE[(size_t)bid<<4],(unsigned)(s+1));
  }
  float* hout=dir?P.hb:P.hf;
  f32x4 v; v[0]=hreg[0];v[1]=hreg[1];v[2]=hreg[2];v[3]=hreg[3];
  *(f32x4*)&hout[(size_t)m*H+j0]=v;
}

// ---------------- persistent decoder: 128 blocks x 512 thr ----------------
// bid = mgrp*16 + jb ; mgrp 0..7 (32 rows), jb 0..15 (64 gate-cols / 128 VC-cols)
struct DecP {
  unsigned short *h1b0,*h1b1,*h2b0,*h2b1;
  const unsigned short *w1hh,*w2ih,*w2hh,*wout;
  const float *bhh1,*bih2,*bhh2,*bout;
  const float *zpart,*WT,*h1f;
  float *logits,*lsbuf,*recon;
  unsigned *F1,*F2,*F3,*F4;
};

__global__ __launch_bounds__(512,1) void k_dec(DecP P){
  __shared__ unsigned short L[76288];      // PA [32][RS] @0, PB @33024, SM @66048 (floats)
  const int PB=33024, SMB=66048;
  const int tid=threadIdx.x, wave=tid>>6, lane=tid&63;
  const int l15=lane&15, l4=lane>>4;
  const int bid=blockIdx.x, jb=bid&15, mgrp=bid>>4;
  const int g16=bid&~15;
  const int jt4=wave>>1, mi=wave&1;
  const int jrow=jb*64+jt4*16+l15;
  const int j0=jb*64+jt4*16+(l4<<2);
  const int m=mgrp*32+mi*16+l15;
  const int nrow0=jb*128+jt4*32+l15;
  const int n0=jb*128+jt4*32+(l4<<2);
  unsigned short* h1b[2]={P.h1b0,P.h1b1};
  unsigned short* h2b[2]={P.h2b0,P.h2b1};

  f32x4 zR4=*(const f32x4*)&P.zpart[(size_t)m*G3+j0];
  f32x4 zZ4=*(const f32x4*)&P.zpart[(size_t)m*G3+H+j0];
  f32x4 zN4=*(const f32x4*)&P.zpart[(size_t)m*G3+2*H+j0];
  f32x4 b1R=*(const f32x4*)&P.bhh1[j0], b1Z=*(const f32x4*)&P.bhh1[H+j0], b1N=*(const f32x4*)&P.bhh1[2*H+j0];
  f32x4 c2R,c2Z,biN2,bhN2;
  { f32x4 a=*(const f32x4*)&P.bih2[j0],   b2=*(const f32x4*)&P.bhh2[j0];   c2R=a+b2; }
  { f32x4 a=*(const f32x4*)&P.bih2[H+j0], b2=*(const f32x4*)&P.bhh2[H+j0]; c2Z=a+b2; }
  biN2=*(const f32x4*)&P.bih2[2*H+j0]; bhN2=*(const f32x4*)&P.bhh2[2*H+j0];
  f32x4 bo0=*(const f32x4*)&P.bout[n0];
  f32x4 bo1=*(const f32x4*)&P.bout[n0+16];
  f32x4 h1i=*(const f32x4*)&P.h1f[(size_t)m*H+j0];
  float h1reg[4]={h1i[0],h1i[1],h1i[2],h1i[3]};
  float h2reg[4]={};

  auto gather=[&](int base, const unsigned short* src, unsigned* F, unsigned tgt){
    const int p=tid>>5, u=tid&31;
    const unsigned* fa=&F[(size_t)(g16+p)<<4];
    while (ldc4(fa)<tgt) __builtin_amdgcn_s_sleep(1);
    cmb();
    const unsigned short* s=src + (size_t)(mgrp*32+u)*H + p*64;
    unsigned long long q[16];
#pragma unroll
    for (int i=0;i<16;++i) q[i]=ldc8(s+i*4);
    unsigned short* d=&L[base + u*RS + p*64];
#pragma unroll
    for (int i=0;i<16;++i) *(unsigned long long*)&d[i*4]=q[i];
  };
  auto PF=[&](int base,int kk)->bf16x8{
    return *(const bf16x8*)&L[base + (mi*16+l15)*RS + kk*32 + l4*8];
  };

  // t=0: preload PA = h1b0 panel (no flags; data from k_h1init)
  { const int p=tid>>5, u=tid&31;
    const unsigned short* s=P.h1b0 + (size_t)(mgrp*32+u)*H + p*64;
    unsigned long long q[16];
#pragma unroll
    for (int i=0;i<16;++i) q[i]=ldc8(s+i*4);
    unsigned short* d=&L[u*RS + p*64];
#pragma unroll
    for (int i=0;i<16;++i) *(unsigned long long*)&d[i*4]=q[i];
  }
  __syncthreads();

  for (int t=0;t<NSTEP;++t){
    const int cur=t&1, nxt=cur^1;
    // ========== stage1: GEMM wait-free (PA = h1[cur]); F4 only at combine ==========
    {
      f32x4 aR={},aZ={},aN={};
#pragma unroll 4
      for (int kk=0;kk<32;++kk){
        bf16x8 b=PF(0,kk);
        bf16x8 a0=*(const bf16x8*)&P.w1hh[(size_t)(jrow      )*H + kk*32 + l4*8];
        bf16x8 a1=*(const bf16x8*)&P.w1hh[(size_t)(H   +jrow )*H + kk*32 + l4*8];
        bf16x8 a2=*(const bf16x8*)&P.w1hh[(size_t)(2*H +jrow )*H + kk*32 + l4*8];
        aR=MFMA(a0,b,aR); aZ=MFMA(a1,b,aZ); aN=MFMA(a2,b,aN);
      }
      unsigned fv=waitseq(P.F4,g16,16,(unsigned)t);
      int rr=mi*16+l15;
      unsigned vv=__shfl(fv,rr>>1);
      int idxm=(int)((vv>>(12*(rr&1)))&0xfffu);
      const float* wtr=P.WT+(size_t)idxm*G3;
      f32x4 wR=*(const f32x4*)&wtr[j0];
      f32x4 wZ=*(const f32x4*)&wtr[H+j0];
      f32x4 wN=*(const f32x4*)&wtr[2*H+j0];
      float hv[4];
#pragma unroll
      for (int r=0;r<4;++r){
        float rg=sigm(zR4[r]+wR[r]+aR[r]+b1R[r]);
        float zg=sigm(zZ4[r]+wZ[r]+aZ[r]+b1Z[r]);
        float nn=tanhf(zN4[r]+wN[r]+rg*(aN[r]+b1N[r]));
        float hnew=(1.f-zg)*nn+zg*h1reg[r];
        h1reg[r]=hnew; hv[r]=hnew;
      }
      stc8(h1b[nxt]+(size_t)m*H+j0, pack4(hv[0],hv[1],hv[2],hv[3]));
      drain(); __syncthreads();
      if (tid==0) stc4(&P.F1[(size_t)bid<<4],(unsigned)(t+1));
    }
    // ========== stage2: gh2 half wait-free (PB = h2[cur]); then gather h1-new ==========
    {
      f32x4 aR={},aZ={},aNI={},aNH={};
      if (t>0){
#pragma unroll 4
        for (int kk=0;kk<32;++kk){
          bf16x8 b=PF(PB,kk);
          bf16x8 a0=*(const bf16x8*)&P.w2hh[(size_t)(jrow      )*H + kk*32 + l4*8];
          bf16x8 a1=*(const bf16x8*)&P.w2hh[(size_t)(H   +jrow )*H + kk*32 + l4*8];
          bf16x8 a2=*(const bf16x8*)&P.w2hh[(size_t)(2*H +jrow )*H + kk*32 + l4*8];
          aR=MFMA(a0,b,aR); aZ=MFMA(a1,b,aZ); aNH=MFMA(a2,b,aNH);
        }
      }
      gather(0, h1b[nxt], P.F1, (unsigned)(t+1));
      __syncthreads();
#pragma unroll 2
      for (int kk=0;kk<32;++kk){
        bf16x8 b=PF(0,kk);
        bf16x8 a0=*(const bf16x8*)&P.w2ih[(size_t)(jrow      )*H + kk*32 + l4*8];
        bf16x8 a1=*(const bf16x8*)&P.w2ih[(size_t)(H   +jrow )*H + kk*32 + l4*8];
        bf16x8 a2=*(const bf16x8*)&P.w2ih[(size_t)(2*H +jrow )*H + kk*32 + l4*8];
        aR=MFMA(a0,b,aR); aZ=MFMA(a1,b,aZ); aNI=MFMA(a2,b,aNI);
        if (t==0){
          bf16x8 c0=*(const bf16x8*)&P.w2hh[(size_t)(jrow      )*H + kk*32 + l4*8];
          bf16x8 c1=*(const bf16x8*)&P.w2hh[(size_t)(H   +jrow )*H + kk*32 + l4*8];
          bf16x8 c2=*(const bf16x8*)&P.w2hh[(size_t)(2*H +jrow )*H + kk*32 + l4*8];
          aR=MFMA(c0,b,aR); aZ=MFMA(c1,b,aZ); aNH=MFMA(c2,b,aNH);
        }
      }
      float hv[4];
#pragma unroll
      for (int r=0;r<4;++r){
        float rg=sigm(aR[r]+c2R[r]);
        float zg=sigm(aZ[r]+c2Z[r]);
        float nn=tanhf(aNI[r]+biN2[r]+rg*(aNH[r]+bhN2[r]));
        float hp=(t==0)?h1reg[r]:h2reg[r];
        float hnew=(1.f-zg)*nn+zg*hp;
        h2reg[r]=hnew; hv[r]=hnew;
      }
      stc8(h2b[nxt]+(size_t)m*H+j0, pack4(hv[0],hv[1],hv[2],hv[3]));
      drain(); __syncthreads();
      if (tid==0) stc4(&P.F2[(size_t)bid<<4],(unsigned)(t+1));
    }
    // ========== stage3: gather h2-new -> logits ==========
    {
      gather(PB, h2b[nxt], P.F2, (unsigned)(t+1));
      __syncthreads();
      f32x4 ac0={},ac1={};
#pragma unroll 4
      for (int kk=0;kk<32;++kk){
        bf16x8 b=PF(PB,kk);
        bf16x8 a0=*(const bf16x8*)&P.wout[(size_t)(nrow0   )*H + kk*32 + l4*8];
        bf16x8 a1=*(const bf16x8*)&P.wout[(size_t)(nrow0+16)*H + kk*32 + l4*8];
        ac0=MFMA(a0,b,ac0); ac1=MFMA(a1,b,ac1);
      }
      stc8(&P.logits[(size_t)m*VC+n0],    packf2(ac0[0]+bo0[0],ac0[1]+bo0[1]));
      stc8(&P.logits[(size_t)m*VC+n0+2],  packf2(ac0[2]+bo0[2],ac0[3]+bo0[3]));
      stc8(&P.logits[(size_t)m*VC+n0+16], packf2(ac1[0]+bo1[0],ac1[1]+bo1[1]));
      stc8(&P.logits[(size_t)m*VC+n0+18], packf2(ac1[2]+bo1[2],ac1[3]+bo1[3]));
      drain(); __syncthreads();
      if (tid==0) stc4(&P.F3[(size_t)bid<<4],(unsigned)(t+1));
    }
    // ========== stage4: gather logits rows -> softmax/argmax ==========
    {
      float* SM=(float*)&L[SMB];     // ls[2][2048] @0, rv @4096, ri @4608
      { const int p=tid>>5, u=tid&31;
        const unsigned* fa=&P.F3[(size_t)(g16+p)<<4];
        while (ldc4(fa)<(unsigned)(t+1)) __builtin_amdgcn_s_sleep(1);
        cmb();
        const int row=u>>4, c0=(u&15)*8;
        const float* s=&P.logits[(size_t)(2*bid+row)*VC + p*128 + c0];
#pragma unroll
        for (int i=0;i<4;++i){
          unsigned long long q=ldc8(s+i*2);
          SM[row*2048 + p*128 + c0 + i*2]   = __uint_as_float((unsigned)q);
          SM[row*2048 + p*128 + c0 + i*2+1] = __uint_as_float((unsigned)(q>>32));
        }
      }
      __syncthreads();
      const int row=tid>>8, t2=tid&255;
      if (t2<V){
        float mx=-1e30f;
        for (int c=0;c<C;++c) mx=fmaxf(mx,SM[row*2048+c*V+t2]);
        float su=0.f;
        for (int c=0;c<C;++c) su+=expf(SM[row*2048+c*V+t2]-mx);
        float lse=mx+logf(su);
        for (int c=0;c<C;++c) SM[row*2048+c*V+t2]-=lse;
      }
      __syncthreads();
      float bv=-1e30f; int bi=0;
#pragma unroll
      for (int i=0;i<8;++i){
        int n=t2*8+i; float v=SM[row*2048+n];
        if (v>bv){bv=v;bi=n;}
      }
      float* RV=SM+4096; int* RI=(int*)(SM+4608);
      RV[row*256+t2]=bv; RI[row*256+t2]=bi;
      __syncthreads();
      for (int s2=128;s2>0;s2>>=1){
        if (t2<s2){
          float v2=RV[row*256+t2+s2]; int i2=RI[row*256+t2+s2];
          if (v2>RV[row*256+t2]||(v2==RV[row*256+t2]&&i2<RI[row*256+t2])){RV[row*256+t2]=v2;RI[row*256+t2]=i2;}
        }
        __syncthreads();
      }
      float* dst=P.lsbuf+(size_t)(t&15)*BVC+(size_t)(2*bid+row)*VC;
#pragma unroll
      for (int i=0;i<4;++i)
        stc8(&dst[t2*8+i*2], packf2(SM[row*2048+t2*8+i*2],SM[row*2048+t2*8+i*2+1]));
      drain(); __syncthreads();
      if (tid==0){
        unsigned i0=(unsigned)RI[0], i1=(unsigned)RI[256];
        stc4(&P.F4[(size_t)bid<<4], ((unsigned)(t+1)<<24)|(i1<<12)|i0);
      }
    }
    // ---------- flush 16 staged steps -> recon (rows owned by this block) ----------
    if ((t&15)==15){
      const int t0=t-15;
      const size_t e0=(size_t)bid*4096 + (size_t)tid*8;
#pragma unroll
      for (int pp=0;pp<4;++pp){
        float va[16],vb[16];
#pragma unroll
        for (int j2=0;j2<16;++j2){
          unsigned long long q=ldc8(&P.lsbuf[(size_t)j2*BVC + e0 + pp*2]);
          va[j2]=__uint_as_float((unsigned)q); vb[j2]=__uint_as_float((unsigned)(q>>32));
        }
        float* d0=&P.recon[(e0+pp*2)*NSTEP+t0];
        float* d1=&P.recon[(e0+pp*2+1)*NSTEP+t0];
#pragma unroll
        for (int k=0;k<16;++k){ d0[k]=va[k]; d1[k]=vb[k]; }
      }
    }
  }
}

// ---------------- host orchestration ----------------
extern "C" void kernel_launch(void* const* d_in, const int* in_sizes, int n_in,
                              void* d_out, int out_size, void* d_ws, size_t ws_size,
                              hipStream_t stream) {
  const float* x        = (const float*)d_in[0];
  const float* noise    = (const float*)d_in[1];
  const float* gruf_Wih = (const float*)d_in[2];
  const float* gruf_Whh = (const float*)d_in[3];
  const float* gruf_bih = (const float*)d_in[4];
  const float* gruf_bhh = (const float*)d_in[5];
  const float* grub_Wih = (const float*)d_in[6];
  const float* grub_Whh = (const float*)d_in[7];
  const float* grub_bih = (const float*)d_in[8];
  const float* grub_bhh = (const float*)d_in[9];
  const float* Wmu      = (const float*)d_in[10];
  const float* bmu      = (const float*)d_in[11];
  const float* Wvar     = (const float*)d_in[12];
  const float* bvar     = (const float*)d_in[13];
  const float* Winit    = (const float*)d_in[14];
  const float* binit    = (const float*)d_in[15];
  const float* c1_Wih   = (const float*)d_in[16];
  const float* c1_Whh   = (const float*)d_in[17];
  const float* c1_bih   = (const float*)d_in[18];
  const float* c1_bhh   = (const float*)d_in[19];
  const float* c2_Wih   = (const float*)d_in[20];
  const float* c2_Whh   = (const float*)d_in[21];
  const float* c2_bih   = (const float*)d_in[22];
  const float* c2_bhh   = (const float*)d_in[23];
  const float* Wout     = (const float*)d_in[24];
  const float* bout     = (const float*)d_in[25];

  float* omu = (float*)d_out;
  float* ovar = omu + B*Z;
  float* oz = ovar + B*Z;
  float* orecon = oz + B*Z;

  char* p = (char*)d_ws;
  auto carve = [&](size_t bytes){ char* r = p; p += (bytes+255)&~(size_t)255; return r; };
  unsigned short* wihf_b  = (unsigned short*)carve((size_t)G3*V*2);
  unsigned short* whhf_b  = (unsigned short*)carve((size_t)G3*H*2);
  unsigned short* wihb_b  = (unsigned short*)carve((size_t)G3*V*2);
  unsigned short* whhb_b  = (unsigned short*)carve((size_t)G3*H*2);
  unsigned short* wc1hh_b = (unsigned short*)carve((size_t)G3*H*2);
  unsigned short* wc2ih_b = (unsigned short*)carve((size_t)G3*H*2);
  unsigned short* wc2hh_b = (unsigned short*)carve((size_t)G3*H*2);
  unsigned short* wout_b  = (unsigned short*)carve((size_t)VC*H*2);
  unsigned short* xtb     = (unsigned short*)carve((size_t)S*B*V*2);
  unsigned short* hf0     = (unsigned short*)carve((size_t)B*H*2);
  unsigned short* hf1     = (unsigned short*)carve((size_t)B*H*2);
  unsigned short* hb0     = (unsigned short*)carve((size_t)B*H*2);
  unsigned short* hb1     = (unsigned short*)carve((size_t)B*H*2);
  unsigned short* h1b0    = (unsigned short*)carve((size_t)B*H*2);
  unsigned short* h1b1    = (unsigned short*)carve((size_t)B*H*2);
  unsigned short* h2b0    = (unsigned short*)carve((size_t)B*H*2);
  unsigned short* h2b1    = (unsigned short*)carve((size_t)B*H*2);
  float* WT     = (float*)carve((size_t)VC*G3*4);
  float* zpart  = (float*)carve((size_t)B*G3*4);
  float* hf     = (float*)carve((size_t)B*H*4);
  float* hb     = (float*)carve((size_t)B*H*4);
  float* h1f    = (float*)carve((size_t)B*H*4);
  float* zws    = (float*)carve((size_t)B*Z*4);
  float* logits = (float*)carve((size_t)B*VC*4);
  float* lsbuf  = (float*)carve((size_t)16*BVC*4);
  unsigned* FE  = (unsigned*)carve(16384);
  unsigned* F1  = (unsigned*)carve(8192);
  unsigned* F2  = (unsigned*)carve(8192);
  unsigned* F3  = (unsigned*)carve(8192);
  unsigned* F4  = (unsigned*)carve(8192);

  dim3 b256(256);
  auto cvt=[&](const float* s, unsigned short* d, int n){
    int nb=(n+255)/256; if (nb>2048) nb=2048;
    k_cvt<<<nb,b256,0,stream>>>(s,d,n);
  };
  cvt(gruf_Wih,wihf_b,G3*V);
  cvt(gruf_Whh,whhf_b,G3*H);
  cvt(grub_Wih,wihb_b,G3*V);
  cvt(grub_Whh,whhb_b,G3*H);
  cvt(c1_Whh,wc1hh_b,G3*H);
  cvt(c2_Wih,wc2ih_b,G3*H);
  cvt(c2_Whh,wc2hh_b,G3*H);
  cvt(Wout,wout_b,VC*H);
  k_xt<<<dim3(S/32,(B*V)/32),dim3(32,8),0,stream>>>(x,xtb);
  k_wt<<<dim3(VC/32,G3/32),dim3(32,8),0,stream>>>(c1_Wih,WT);
  hipMemsetAsync(hf0,0,(size_t)B*H*2,stream);
  hipMemsetAsync(hb0,0,(size_t)B*H*2,stream);
  hipMemsetAsync(FE,0,16384+4*8192,stream);   // FE,F1..F4 contiguous

  EncP ep;
  ep.xtb=xtb; ep.wihf=wihf_b; ep.whhf=whhf_b; ep.wihb=wihb_b; ep.whhb=whhb_b;
  ep.bihf=gruf_bih; ep.bhhf=gruf_bhh; ep.bihb=grub_bih; ep.bhhb=grub_bhh;
  ep.hf0=hf0; ep.hf1=hf1; ep.hb0=hb0; ep.hb1=hb1;
  ep.hf=hf; ep.hb=hb; ep.FE=FE;
  k_enc<<<256,dim3(512),0,stream>>>(ep);

  k_mu_var_z<<<B,b256,0,stream>>>(hf,hb,Wmu,bmu,Wvar,bvar,noise,omu,ovar,oz,zws);
  k_zpart<<<B*G3/256,b256,0,stream>>>(zws,c1_Wih,c1_bih,zpart);
  k_h1init<<<B*H/256,b256,0,stream>>>(zws,Winit,binit,h1f,h1b0,F4);

  DecP dp;
  dp.h1b0=h1b0; dp.h1b1=h1b1; dp.h2b0=h2b0; dp.h2b1=h2b1;
  dp.w1hh=wc1hh_b; dp.w2ih=wc2ih_b; dp.w2hh=wc2hh_b; dp.wout=wout_b;
  dp.bhh1=c1_bhh; dp.bih2=c2_bih; dp.bhh2=c2_bhh; dp.bout=bout;
  dp.zpart=zpart; dp.WT=WT; dp.h1f=h1f;
  dp.logits=logits; dp.lsbuf=lsbuf; dp.recon=orecon;
  dp.F1=F1; dp.F2=F2; dp.F3=F3; dp.F4=F4;
  k_dec<<<128,dim3(512),0,stream>>>(dp);
}